// Round 17
// baseline (2403.705 us; speedup 1.0000x reference)
//
#include <hip/hip_runtime.h>
#include <hip/hip_bf16.h>
#include <math.h>

#define BATCH 128
#define TT    12
#define CIN   10
#define HID   64
#define PLANE 625
#define IPB   50000       // shorts per batch image in inp: 10 units * 625 * 8
#define NKB   45
#define NKB_ALLOC (NKB+6)
#define CSZ   (BATCH*PLANE*HID)
#define KSPLIT 10
#define NPIX  405         // A-tile: 15 rows x 27 cols
#define USTR  (NPIX*8)    // 3240 shorts per k-half unit
#define CISTR (2*NPIX*8)  // 6480 shorts per ci step

typedef __attribute__((ext_vector_type(8)))  short bf16x8;
typedef __attribute__((ext_vector_type(16))) float f32x16;

__device__ __forceinline__ float fsigm(float v){ return 1.f/(1.f+__expf(-v)); }
__device__ __forceinline__ float ftanh(float v){ return 1.f - 2.f/(__expf(2.f*v)+1.f); }
__device__ __forceinline__ unsigned short f2bf(float v){
    __hip_bfloat16 b = __float2bfloat16(v);
    return *reinterpret_cast<unsigned short*>(&b);
}

// ---- prepack conv_w -> B fragments (verified layout, unchanged) ----
__global__ void k_wprep(const float* __restrict__ w, unsigned short* __restrict__ wpk){
    int tid = blockIdx.x*256 + threadIdx.x;
    if (tid >= NKB*8*64) return;
    int lane = tid & 63;
    int nt   = (tid >> 6) & 7;
    int kb   = tid >> 9;
    int tap = kb/5, ci = kb - tap*5;
    int ky = tap/3, kx = tap - ky*3;
    int g = lane & 3, jlo = (lane & 31) >> 2, kh = lane >> 5;
    int o = g*64 + nt*8 + jlo;
    union { unsigned short u[8]; float4 f; } pk;
    #pragma unroll
    for (int e = 0; e < 8; ++e){
        int ch = ci*16 + kh*8 + e;
        float v = (ch < 74) ? w[((o*74 + ch)*3 + ky)*3 + kx] : 0.f;
        pk.u[e] = f2bf(v);
    }
    *reinterpret_cast<float4*>(wpk + (size_t)tid*8) = pk.f;
}

__global__ void k_w1prep(const float* __restrict__ w1, float* __restrict__ w1t){
    int tid = blockIdx.x*256 + threadIdx.x;
    if (tid >= 40000*4) return;
    int rowp = tid >> 2, f4 = tid & 3;
    int m = rowp >> 6, j = rowp & 63;
    const float4* src = (const float4*)(w1 + (size_t)(j*625 + m)*16);
    ((float4*)(w1t + (size_t)rowp*16))[f4] = src[f4];
}

__global__ void k_xcopy(const float* __restrict__ x, unsigned short* __restrict__ inp, int t){
    int idx = blockIdx.x*256 + threadIdx.x;
    if (idx >= BATCH*CIN*PLANE) return;
    int m  = idx % PLANE;
    int r  = idx / PLANE;
    int ch = r % CIN;
    int b  = r / CIN;
    float v = x[((size_t)(b*TT + t)*CIN + ch)*PLANE + m];
    inp[(size_t)b*IPB + ((((ch>>3)*PLANE) + m)<<3) + (ch&7)] = f2bf(v);
}

// ---- PERSISTENT fused ConvLSTM: all 12 timesteps in one kernel ----
// grid (2 halves, 128 batch) = 256 blocks = 1/CU guaranteed resident (deadlock-safe).
// half0: output rows 0..12 (m 0..324), half1: rows 13..24 (m 325..624).
// 512 thr = 8 waves = 4 nt-pairs x 2 m-groups; wave = 2nt x 6mt (12 MFMA chains).
// Per step: stage 15-row A-tile (64.8KB LDS, incl 1 halo row from neighbor) ->
// K-loop -> LSTM epilogue -> x-copy -> release flag; spin-acquire neighbor's flag.
// Rationale (R12-R16 post-mortems): every intra-kernel lever was null; the ~50us/step
// invariant is inter-launch convoy + per-step setup, which this removes.
__global__ __launch_bounds__(512, 2) void k_conv(
    const float* __restrict__ x,
    unsigned short* __restrict__ inp0,
    unsigned short* __restrict__ inp1,
    const unsigned short* __restrict__ wpk,
    const float* __restrict__ bias,
    float* __restrict__ cbuf,
    unsigned short* __restrict__ hbf,
    int* __restrict__ flags)
{
    __shared__ __align__(16) unsigned short at2[10*NPIX*8];   // 64.8 KB

    const int tid  = threadIdx.x;
    const int half = blockIdx.x;
    const int b    = blockIdx.y;
    const int lane = tid & 63;
    const int w    = tid >> 6;
    const int ntp  = w & 3;                   // nt pair: nt0 = 2*ntp
    const int mh   = w >> 2;                  // m-group: mt = mh*6 + q
    const int gr0  = half ? 12 : -1;          // tile row 0 = global row gr0
    const int mb0  = half ? 325 : 0;          // first output m of this half
    const int kh   = lane >> 5;

    // per-lane A bases for 6 m-tiles (dummy tiles clamp to m=624; epilogue guards)
    const unsigned short* ab[6];
    int mtbase[6];
    #pragma unroll
    for (int q = 0; q < 6; ++q){
        int base = mb0 + (mh*6 + q)*32;
        mtbase[q] = base;
        int m0 = base + (lane & 31);
        if (m0 > 624) m0 = 624;
        int row = m0/25, col = m0 - row*25;
        ab[q] = at2 + kh*USTR + (((row - 1 - gr0)*27 + col) << 3);
    }

    const int g   = lane & 3;
    const int jlo = (lane & 31) >> 2;
    const int j0  = (ntp*2+0)*8 + jlo;
    const int j1  = (ntp*2+1)*8 + jlo;
    const float bown0 = bias[g*64 + j0];
    const float bown1 = bias[g*64 + j1];
    const float sA = (g == 3) ? 2.f : 1.f;
    const float sB = (g == 3) ? -1.f : 0.f;
    const bool gb0 = (g & 1), gb1 = (g & 2);
    float* cb = cbuf + (size_t)b*PLANE*HID;
    unsigned short* hfb = hbf + (size_t)b*40000;
    const int chh0 = CIN + j0, uh0 = chh0 >> 3, sh0 = chh0 & 7;
    const int chh1 = CIN + j1, uh1 = chh1 >> 3, sh1 = chh1 & 7;
    const int mcount = half ? 300 : 325;
    int* const fown  = flags + (b*2 + half)*16;
    int* const fothr = flags + (b*2 + (half^1))*16;

    for (int t = 0; t < TT; ++t){
        const unsigned short* ic  = (t & 1) ? inp1 : inp0;
        unsigned short*       in_ = (t & 1) ? inp0 : inp1;
        const unsigned short* ib  = ic  + (size_t)b*IPB;
        unsigned short*       hn  = in_ + (size_t)b*IPB;

        // ---- stage A-tile: rows gr0..gr0+14, cols -1..25, zero pads ----
        for (int idx = tid; idx < 10*NPIX; idx += 512){
            int u   = idx/NPIX, pix = idx - u*NPIX;
            int rr  = pix/27,   cc  = pix - rr*27;
            int gr  = gr0 + rr, gc = cc - 1;
            float4 v = {0.f,0.f,0.f,0.f};
            if ((unsigned)gr < 25u && (unsigned)gc < 25u)
                v = *reinterpret_cast<const float4*>(ib + (((size_t)u*PLANE + gr*25 + gc)<<3));
            *reinterpret_cast<float4*>(at2 + ((size_t)idx<<3)) = v;
        }

        f32x16 acc[6][2];
        #pragma unroll
        for (int q = 0; q < 6; ++q)
            #pragma unroll
            for (int n = 0; n < 2; ++n)
                #pragma unroll
                for (int e = 0; e < 16; ++e) acc[q][n][e] = 0.f;

        __syncthreads();

        // ---- K loop: 9 taps x 5 ci; 12 MFMA chains per wave ----
        const bf16x8* wtap = reinterpret_cast<const bf16x8*>(wpk) + (ntp*2)*64 + lane;
        const unsigned short *a0 = ab[0], *a1 = ab[1], *a2 = ab[2],
                             *a3 = ab[3], *a4 = ab[4], *a5 = ab[5];
        #pragma unroll 1
        for (int tap = 0; tap < 9; ++tap){
            #pragma unroll
            for (int ci = 0; ci < 5; ++ci){
                bf16x8 B0 = wtap[ci*512];
                bf16x8 B1 = wtap[ci*512 + 64];
                bf16x8 f0 = *reinterpret_cast<const bf16x8*>(a0 + ci*CISTR);
                bf16x8 f1 = *reinterpret_cast<const bf16x8*>(a1 + ci*CISTR);
                bf16x8 f2 = *reinterpret_cast<const bf16x8*>(a2 + ci*CISTR);
                bf16x8 f3 = *reinterpret_cast<const bf16x8*>(a3 + ci*CISTR);
                bf16x8 f4 = *reinterpret_cast<const bf16x8*>(a4 + ci*CISTR);
                bf16x8 f5 = *reinterpret_cast<const bf16x8*>(a5 + ci*CISTR);
                acc[0][0] = __builtin_amdgcn_mfma_f32_32x32x16_bf16(f0, B0, acc[0][0], 0,0,0);
                acc[0][1] = __builtin_amdgcn_mfma_f32_32x32x16_bf16(f0, B1, acc[0][1], 0,0,0);
                acc[1][0] = __builtin_amdgcn_mfma_f32_32x32x16_bf16(f1, B0, acc[1][0], 0,0,0);
                acc[1][1] = __builtin_amdgcn_mfma_f32_32x32x16_bf16(f1, B1, acc[1][1], 0,0,0);
                acc[2][0] = __builtin_amdgcn_mfma_f32_32x32x16_bf16(f2, B0, acc[2][0], 0,0,0);
                acc[2][1] = __builtin_amdgcn_mfma_f32_32x32x16_bf16(f2, B1, acc[2][1], 0,0,0);
                acc[3][0] = __builtin_amdgcn_mfma_f32_32x32x16_bf16(f3, B0, acc[3][0], 0,0,0);
                acc[3][1] = __builtin_amdgcn_mfma_f32_32x32x16_bf16(f3, B1, acc[3][1], 0,0,0);
                acc[4][0] = __builtin_amdgcn_mfma_f32_32x32x16_bf16(f4, B0, acc[4][0], 0,0,0);
                acc[4][1] = __builtin_amdgcn_mfma_f32_32x32x16_bf16(f4, B1, acc[4][1], 0,0,0);
                acc[5][0] = __builtin_amdgcn_mfma_f32_32x32x16_bf16(f5, B0, acc[5][0], 0,0,0);
                acc[5][1] = __builtin_amdgcn_mfma_f32_32x32x16_bf16(f5, B1, acc[5][1], 0,0,0);
            }
            const int d = (tap == 2 || tap == 5) ? 25*8 : 8;
            a0 += d; a1 += d; a2 += d; a3 += d; a4 += d; a5 += d;
            wtap += 2560;
        }

        // ---- LSTM epilogue: quad transpose -> all lanes update ----
        #pragma unroll
        for (int q = 0; q < 6; ++q){
            #pragma unroll
            for (int n = 0; n < 2; ++n){
                const int   jj = n ? j1 : j0;
                const float bw = n ? bown1 : bown0;
                const int   uh = n ? uh1 : uh0;
                const int   sh = n ? sh1 : sh0;
                #pragma unroll
                for (int rq = 0; rq < 4; ++rq){
                    float v0 = fmaf(sA, fsigm(sA*(acc[q][n][rq*4+0] + bw)), sB);
                    float v1 = fmaf(sA, fsigm(sA*(acc[q][n][rq*4+1] + bw)), sB);
                    float v2 = fmaf(sA, fsigm(sA*(acc[q][n][rq*4+2] + bw)), sB);
                    float v3 = fmaf(sA, fsigm(sA*(acc[q][n][rq*4+3] + bw)), sB);
                    float s;
                    s = __shfl_xor(gb0 ? v0 : v1, 1); if (gb0) v0 = s; else v1 = s;
                    s = __shfl_xor(gb0 ? v2 : v3, 1); if (gb0) v2 = s; else v3 = s;
                    s = __shfl_xor(gb1 ? v0 : v2, 2); if (gb1) v0 = s; else v2 = s;
                    s = __shfl_xor(gb1 ? v1 : v3, 2); if (gb1) v1 = s; else v3 = s;
                    const int m = mtbase[q] + 4*kh + g + 8*rq;
                    if (m < PLANE){
                        float co = cb[m*HID + jj];
                        float cn = fmaf(v1, co, v0*v3);
                        float h  = v2 * ftanh(cn);
                        if (t < TT-1){
                            cb[m*HID + jj] = cn;
                            hn[((uh*PLANE + m) << 3) + sh] = f2bf(h);
                        } else {
                            hfb[m*64 + jj] = f2bf(h > 0.f ? h : 0.f);
                        }
                    }
                }
            }
        }

        if (t < TT-1){
            // ---- x-copy for step t+1 (own m-range) ----
            const float* xn = x + (size_t)(b*TT + t + 1)*CIN*PLANE;
            #pragma unroll 1
            for (int ch = 0; ch < CIN; ++ch){
                for (int mi = tid; mi < mcount; mi += 512){
                    int m = mb0 + mi;
                    hn[(((ch>>3)*PLANE + m)<<3) + (ch&7)] = f2bf(xn[ch*PLANE + m]);
                }
            }
            // ---- release own step-t outputs; acquire neighbor's ----
            __threadfence();
            __syncthreads();                  // also WAR-protects at2 restaging
            if (tid == 0){
                atomicExch(&fown[t], 1);
                while (atomicAdd(&fothr[t], 0) == 0) __builtin_amdgcn_s_sleep(8);
            }
            __syncthreads();
            __threadfence();
        }
    }
}

// -------- MLP stage 1 (unchanged) --------
__global__ __launch_bounds__(256) void k_mlp1(
    const unsigned short* __restrict__ hbf, const float* __restrict__ w1t,
    float* __restrict__ part)
{
    __shared__ float xw[4][4][16];
    const int ks = blockIdx.x, bg = blockIdx.y, tid = threadIdx.x;
    const int kw0 = ks*4000, kw1 = kw0 + 4000;
    const unsigned short* h0 = hbf + (size_t)(bg*4+0)*40000;
    const unsigned short* h1 = hbf + (size_t)(bg*4+1)*40000;
    const unsigned short* h2 = hbf + (size_t)(bg*4+2)*40000;
    const unsigned short* h3 = hbf + (size_t)(bg*4+3)*40000;

    float acc[4][16];
    #pragma unroll
    for (int bi = 0; bi < 4; ++bi)
        #pragma unroll
        for (int n = 0; n < 16; ++n) acc[bi][n] = 0.f;

    for (int kw = kw0 + tid*2; kw < kw1; kw += 512){
        const float4* wp = (const float4*)(w1t + (size_t)kw*16);
        float4 q0 = wp[0], q1 = wp[1], q2 = wp[2], q3 = wp[3];
        float4 r0 = wp[4], r1 = wp[5], r2 = wp[6], r3 = wp[7];
        unsigned int u0 = *(const unsigned int*)(h0 + kw);
        unsigned int u1 = *(const unsigned int*)(h1 + kw);
        unsigned int u2 = *(const unsigned int*)(h2 + kw);
        unsigned int u3 = *(const unsigned int*)(h3 + kw);
        #define ACC1(bi, u) { \
            float fl = __uint_as_float((u) << 16); \
            float fh = __uint_as_float((u) & 0xffff0000u); \
            acc[bi][ 0]=fmaf(fl,q0.x,fmaf(fh,r0.x,acc[bi][ 0])); \
            acc[bi][ 1]=fmaf(fl,q0.y,fmaf(fh,r0.y,acc[bi][ 1])); \
            acc[bi][ 2]=fmaf(fl,q0.z,fmaf(fh,r0.z,acc[bi][ 2])); \
            acc[bi][ 3]=fmaf(fl,q0.w,fmaf(fh,r0.w,acc[bi][ 3])); \
            acc[bi][ 4]=fmaf(fl,q1.x,fmaf(fh,r1.x,acc[bi][ 4])); \
            acc[bi][ 5]=fmaf(fl,q1.y,fmaf(fh,r1.y,acc[bi][ 5])); \
            acc[bi][ 6]=fmaf(fl,q1.z,fmaf(fh,r1.z,acc[bi][ 6])); \
            acc[bi][ 7]=fmaf(fl,q1.w,fmaf(fh,r1.w,acc[bi][ 7])); \
            acc[bi][ 8]=fmaf(fl,q2.x,fmaf(fh,r2.x,acc[bi][ 8])); \
            acc[bi][ 9]=fmaf(fl,q2.y,fmaf(fh,r2.y,acc[bi][ 9])); \
            acc[bi][10]=fmaf(fl,q2.z,fmaf(fh,r2.z,acc[bi][10])); \
            acc[bi][11]=fmaf(fl,q2.w,fmaf(fh,r2.w,acc[bi][11])); \
            acc[bi][12]=fmaf(fl,q3.x,fmaf(fh,r3.x,acc[bi][12])); \
            acc[bi][13]=fmaf(fl,q3.y,fmaf(fh,r3.y,acc[bi][13])); \
            acc[bi][14]=fmaf(fl,q3.z,fmaf(fh,r3.z,acc[bi][14])); \
            acc[bi][15]=fmaf(fl,q3.w,fmaf(fh,r3.w,acc[bi][15])); }
        ACC1(0, u0) ACC1(1, u1) ACC1(2, u2) ACC1(3, u3)
        #undef ACC1
    }

    #pragma unroll
    for (int d = 1; d < 64; d <<= 1)
        #pragma unroll
        for (int bi = 0; bi < 4; ++bi)
            #pragma unroll
            for (int n = 0; n < 16; ++n) acc[bi][n] += __shfl_xor(acc[bi][n], d);
    if ((tid & 63) == 0){
        int w = tid >> 6;
        #pragma unroll
        for (int bi = 0; bi < 4; ++bi)
            #pragma unroll
            for (int n = 0; n < 16; ++n) xw[w][bi][n] = acc[bi][n];
    }
    __syncthreads();
    if (tid < 64){
        int bi = tid >> 4, n = tid & 15;
        float s = xw[0][bi][n] + xw[1][bi][n] + xw[2][bi][n] + xw[3][bi][n];
        part[((size_t)(bg*4 + bi)*KSPLIT + ks)*16 + n] = s;
    }
}

// -------- MLP stage 2 (unchanged) --------
__global__ __launch_bounds__(128) void k_mlp2(
    const float* __restrict__ part,
    const float* __restrict__ b1,
    const float* __restrict__ w2, const float* __restrict__ b2,
    const float* __restrict__ w3, const float* __restrict__ b3,
    float* __restrict__ out)
{
    const int b = threadIdx.x;
    float h1[16];
    #pragma unroll
    for (int i = 0; i < 16; ++i) h1[i] = b1[i];
    for (int s = 0; s < KSPLIT; ++s)
        #pragma unroll
        for (int i = 0; i < 16; ++i) h1[i] += part[((size_t)b * KSPLIT + s) * 16 + i];
    #pragma unroll
    for (int i = 0; i < 16; ++i) h1[i] = h1[i] > 0.f ? h1[i] : 0.f;

    float h2[8];
    #pragma unroll
    for (int i = 0; i < 8; ++i){
        float s2 = b2[i];
        #pragma unroll
        for (int k2 = 0; k2 < 16; ++k2) s2 += h1[k2] * w2[k2*8 + i];
        h2[i] = s2 > 0.f ? s2 : 0.f;
    }
    float l0 = b3[0], l1 = b3[1];
    #pragma unroll
    for (int k3 = 0; k3 < 8; ++k3){ l0 += h2[k3]*w3[k3*2]; l1 += h2[k3]*w3[k3*2+1]; }
    float m   = fmaxf(l0, l1);
    float lse = m + logf(__expf(l0 - m) + __expf(l1 - m));
    out[b*2 + 0] = l0 - lse;
    out[b*2 + 1] = l1 - lse;
}

extern "C" void kernel_launch(void* const* d_in, const int* in_sizes, int n_in,
                              void* d_out, int out_size, void* d_ws, size_t ws_size,
                              hipStream_t stream) {
    const float* x      = (const float*)d_in[0];
    const float* conv_w = (const float*)d_in[1];
    const float* conv_b = (const float*)d_in[2];
    const float* w1     = (const float*)d_in[3];
    const float* b1     = (const float*)d_in[4];
    const float* w2     = (const float*)d_in[5];
    const float* b2     = (const float*)d_in[6];
    const float* w3     = (const float*)d_in[7];
    const float* b3     = (const float*)d_in[8];
    float* out = (float*)d_out;

    unsigned short* inp0 = (unsigned short*)d_ws;
    unsigned short* inp1 = inp0 + (size_t)BATCH*IPB;
    float* c   = (float*)(inp1 + (size_t)BATCH*IPB);
    unsigned short* hbf = (unsigned short*)(c + CSZ);
    unsigned short* wpk = hbf + (size_t)BATCH*40000;
    float* w1t  = (float*)(wpk + (size_t)NKB_ALLOC*8*64*8);
    float* part = w1t + 640000;
    int*   flags = (int*)(part + BATCH*KSPLIT*16);   // [128][2][16] ints

    // ws poisoned once, replays leave state -> re-init everything each call
    hipMemsetAsync(inp0,  0, (size_t)BATCH*IPB*2, stream);
    hipMemsetAsync(inp1,  0, (size_t)BATCH*IPB*2, stream);
    hipMemsetAsync(c,     0, (size_t)CSZ*4,       stream);
    hipMemsetAsync(flags, 0, (size_t)BATCH*2*16*4, stream);

    k_wprep <<<dim3(90),   dim3(256), 0, stream>>>(conv_w, wpk);
    k_w1prep<<<dim3(625),  dim3(256), 0, stream>>>(w1, w1t);
    k_xcopy <<<dim3(3125), dim3(256), 0, stream>>>(x, inp0, 0);

    k_conv<<<dim3(2, BATCH), dim3(512), 0, stream>>>(x, inp0, inp1, wpk, conv_b,
                                                     c, hbf, flags);

    k_mlp1<<<dim3(KSPLIT, 32), dim3(256), 0, stream>>>(hbf, w1t, part);
    k_mlp2<<<dim3(1), dim3(128), 0, stream>>>(part, b1, w2, b2, w3, b3, out);
}